// Round 2
// baseline (1040.190 us; speedup 1.0000x reference)
//
#include <hip/hip_runtime.h>
#include <hip/hip_bf16.h>
#include <math.h>

typedef __bf16 bf16;
typedef __bf16 bf16x2 __attribute__((ext_vector_type(2)));
typedef __bf16 bf16x8 __attribute__((ext_vector_type(8)));
typedef float f32x4 __attribute__((ext_vector_type(4)));

#define NNODES 50000
#define NEDGES 800000

// ============================================================================
// dtype detect: bf16-packed words have bits 15:8 = sign+exp[7:1] of elem 2i
// (concentrated in [0x34,0x43] for ~N(0,1) data); fp32 words have uniform
// mantissa bits there. flag=1 -> inputs are fp32.
// ============================================================================
__global__ void detect_kernel(const unsigned int* __restrict__ xw, int* __restrict__ flag)
{
    const int l = threadIdx.x;  // 64 threads
    int c = 0;
    for (int i = l; i < 4096; i += 64) {
        const unsigned int b1 = (xw[i] >> 8) & 0x7Fu;
        c += (b1 >= 0x34u && b1 <= 0x43u) ? 1 : 0;
    }
#pragma unroll
    for (int off = 32; off; off >>= 1) c += __shfl_xor(c, off);
    if (l == 0) *flag = (c < 2048) ? 1 : 0;
}

__global__ __launch_bounds__(256) void zero_out_kernel(void* out, long n, const int* __restrict__ flag)
{
    const int fp32 = *flag;
    const long i = (long)blockIdx.x * 256 + threadIdx.x;
    if (i < n) {
        if (fp32) ((float*)out)[i] = 0.f;
        else ((bf16*)out)[i] = (bf16)0.f;
    }
}

// ============================================================================
// converts: produce bf16 working copies regardless of input dtype
// ============================================================================
__global__ __launch_bounds__(256) void convert_kernel(
    const void* __restrict__ in, bf16* __restrict__ out, int n, const int* __restrict__ flag)
{
    const int fp32 = *flag;
    const int i = blockIdx.x * 256 + threadIdx.x;
    if (i >= n) return;
    out[i] = fp32 ? (bf16)(((const float*)in)[i]) : ((const bf16*)in)[i];
}

struct CvtBatch { const void* in[16]; bf16* out[16]; int n[16]; };

__global__ __launch_bounds__(256) void convert_batch_kernel(CvtBatch b, const int* __restrict__ flag)
{
    const int fp32 = *flag;
    const int it = blockIdx.y;
    const int n = b.n[it];
    const void* in = b.in[it];
    bf16* out = b.out[it];
    for (int i = blockIdx.x * 256 + threadIdx.x; i < n; i += gridDim.x * 256)
        out[i] = fp32 ? (bf16)(((const float*)in)[i]) : ((const bf16*)in)[i];
}

// ============================================================================
// GEMM: C[M,N] = A[M,K] * B[N,K]^T  (bf16 in/out, fp32 acc), 128x128 tile,
// BK=32, 4 waves 2x2, 4x4 of mfma 16x16x32. Synchronous VGPR->LDS staging.
// ============================================================================
__global__ __launch_bounds__(256) void gemm_bt(
    const bf16* __restrict__ A, const bf16* __restrict__ B,
    bf16* __restrict__ C, int M, int N, int K)
{
    __shared__ __align__(16) bf16 As[128 * 32];
    __shared__ __align__(16) bf16 Bs[128 * 32];
    const int tid  = threadIdx.x;
    const int lane = tid & 63;
    const int w    = tid >> 6;
    const int wm   = (w >> 1) * 64, wn = (w & 1) * 64;
    const int mBase = blockIdx.x * 128, nBase = blockIdx.y * 128;

    f32x4 acc[4][4];
#pragma unroll
    for (int i = 0; i < 4; i++)
#pragma unroll
        for (int j = 0; j < 4; j++)
#pragma unroll
            for (int r = 0; r < 4; r++) acc[i][j][r] = 0.f;

    const int rA   = tid >> 2;
    const int kseg = (tid & 3) * 8;
    int ra0 = mBase + rA;       if (ra0 > M - 1) ra0 = M - 1;
    int ra1 = mBase + rA + 64;  if (ra1 > M - 1) ra1 = M - 1;
    const bf16* gA0 = A + (long)ra0 * K + kseg;
    const bf16* gA1 = A + (long)ra1 * K + kseg;
    const bf16* gB0 = B + (long)(nBase + rA) * K + kseg;
    const bf16* gB1 = B + (long)(nBase + rA + 64) * K + kseg;
    bf16* lA0 = &As[tid * 8];
    bf16* lA1 = &As[(tid + 256) * 8];
    bf16* lB0 = &Bs[tid * 8];
    bf16* lB1 = &Bs[(tid + 256) * 8];

    const int quad = lane >> 4, l16 = lane & 15;

    for (int k0 = 0; k0 < K; k0 += 32) {
        const bf16x8 va0 = *(const bf16x8*)(gA0 + k0);
        const bf16x8 va1 = *(const bf16x8*)(gA1 + k0);
        const bf16x8 vb0 = *(const bf16x8*)(gB0 + k0);
        const bf16x8 vb1 = *(const bf16x8*)(gB1 + k0);
        __syncthreads();           // prev iteration's LDS reads done
        *(bf16x8*)lA0 = va0;
        *(bf16x8*)lA1 = va1;
        *(bf16x8*)lB0 = vb0;
        *(bf16x8*)lB1 = vb1;
        __syncthreads();           // stores visible
        bf16x8 af[4], bfr[4];
#pragma unroll
        for (int i = 0; i < 4; i++) {
            af[i]  = *(const bf16x8*)&As[(wm + i * 16 + l16) * 32 + quad * 8];
            bfr[i] = *(const bf16x8*)&Bs[(wn + i * 16 + l16) * 32 + quad * 8];
        }
#pragma unroll
        for (int i = 0; i < 4; i++)
#pragma unroll
            for (int j = 0; j < 4; j++)
                acc[i][j] = __builtin_amdgcn_mfma_f32_16x16x32_bf16(af[i], bfr[j], acc[i][j], 0, 0, 0);
    }

    // C/D layout: col = lane&15, row = (lane>>4)*4 + r  [m89/m91 verified]
#pragma unroll
    for (int i = 0; i < 4; i++) {
        const int row0 = mBase + wm + i * 16 + quad * 4;
#pragma unroll
        for (int j = 0; j < 4; j++) {
            const int colg = nBase + wn + j * 16 + l16;
#pragma unroll
            for (int r = 0; r < 4; r++) {
                const int row = row0 + r;
                if (row < M) C[(long)row * N + colg] = (bf16)acc[i][j][r];
            }
        }
    }
}

// ============================================================================
// alpha[n,h] = sum_c h[n,h,c]*a[h,c]  (fp32 out); one node/block, wave/head
// ============================================================================
template <int H>
__global__ __launch_bounds__(H * 64) void alpha_kernel(
    const bf16* __restrict__ h, const bf16* __restrict__ av,
    const bf16* __restrict__ dv, float* __restrict__ as_out,
    float* __restrict__ ad_out)
{
    const int C = 128, HC = H * C;
    const int n = blockIdx.x;
    const int t = threadIdx.x;
    const int ht = t >> 6, l = t & 63;
    const bf16* hr = h + (long)n * HC + ht * C;
    float ps = 0.f, pd = 0.f;
#pragma unroll
    for (int c0 = 0; c0 < C; c0 += 64) {
        const float hv = (float)hr[c0 + l];
        ps += hv * (float)av[ht * C + c0 + l];
        pd += hv * (float)dv[ht * C + c0 + l];
    }
#pragma unroll
    for (int off = 32; off; off >>= 1) {
        ps += __shfl_xor(ps, off);
        pd += __shfl_xor(pd, off);
    }
    if (l == 0) {
        as_out[(long)n * H + ht] = ps;
        ad_out[(long)n * H + ht] = pd;
    }
}

// ============================================================================
// CSR build
// ============================================================================
__global__ void hist_kernel(const int* __restrict__ dst, int* __restrict__ cnt, int E)
{
    const int e = blockIdx.x * blockDim.x + threadIdx.x;
    if (e < E) atomicAdd(&cnt[dst[e]], 1);
}

__global__ __launch_bounds__(1024) void scan_kernel(
    const int* __restrict__ cnt, int* __restrict__ rowptr, int n)
{
    __shared__ int buf[1024];
    __shared__ int carry_s;
    const int t = threadIdx.x;
    if (t == 0) { carry_s = 0; rowptr[0] = 0; }
    __syncthreads();
    for (int base = 0; base < n; base += 1024) {
        int v = (base + t < n) ? cnt[base + t] : 0;
        buf[t] = v;
        __syncthreads();
        for (int off = 1; off < 1024; off <<= 1) {
            const int add = (t >= off) ? buf[t - off] : 0;
            __syncthreads();
            buf[t] += add;
            __syncthreads();
        }
        const int carry = carry_s;
        if (base + t < n) rowptr[base + t + 1] = carry + buf[t];
        __syncthreads();
        if (t == 0) carry_s = carry + buf[1023];
        __syncthreads();
    }
}

__global__ void fill_kernel(const int* __restrict__ src, const int* __restrict__ dst,
                            const int* __restrict__ rowptr, int* __restrict__ off,
                            int* __restrict__ col, int E)
{
    const int e = blockIdx.x * blockDim.x + threadIdx.x;
    if (e < E) {
        const int d = dst[e];
        const int p = rowptr[d] + atomicAdd(&off[d], 1);
        col[p] = src[e];
    }
}

// ============================================================================
// GAT aggregation, exact two-pass (no max-subtraction; |e|<=60 clamp makes
// exp safe; mathematically identical to reference softmax). One block/node.
// H*128 == TPB*CPT. dflag: nullptr -> bf16 out; else select fp32/bf16.
// ============================================================================
template <int H, int TPB, int CPT>
__global__ __launch_bounds__(TPB) void agg_kernel(
    const bf16* __restrict__ h, const float* __restrict__ asrc,
    const float* __restrict__ adst, const int* __restrict__ rowptr,
    const int* __restrict__ col, const bf16* __restrict__ bias,
    void* __restrict__ outv, const int* __restrict__ dflag, int relu)
{
    const int C = 128, HC = H * C, CH = TPB;
    __shared__ int   s_lds[CH];
    __shared__ float w_lds[H][CH];
    __shared__ float z_s[H];
    const int n = blockIdx.x, t = threadIdx.x;
    const int lane = t & 63, wd = t >> 6;
    const int myhead = (t * CPT) >> 7;
    const int fp32out = dflag ? *dflag : 0;
    const int start = rowptr[n];
    int deg = rowptr[n + 1] - start;
    deg = max(0, min(deg, NEDGES));
    const int total = deg + 1;  // + virtual self-loop

    float ad_loc[H];
#pragma unroll
    for (int hh = 0; hh < H; hh++) ad_loc[hh] = adst[(long)n * H + hh];

    // pass 1: z per head (wave wd handles head wd)
    if (wd < H) {
        float z = 0.f;
        for (int i = lane; i < total; i += 64) {
            int s = (i < deg) ? col[start + i] : n;
            s = min(max(s, 0), NNODES - 1);
            float e = asrc[(long)s * H + wd] + ad_loc[wd];
            e = (e > 0.f) ? e : 0.2f * e;
            e = fminf(fmaxf(e, -60.f), 60.f);
            z += __expf(e);
        }
#pragma unroll
        for (int off = 32; off; off >>= 1) z += __shfl_xor(z, off);
        if (lane == 0) z_s[wd] = z;
    }
    float accv[CPT];
#pragma unroll
    for (int j = 0; j < CPT; j++) accv[j] = 0.f;
    __syncthreads();
    const float rz = 1.f / (z_s[myhead] + 1e-16f);

    // pass 2: stage (s, exp(e)) chunks in LDS, accumulate
    for (int base = 0; base < total; base += CH) {
        const int cnt = min(CH, total - base);
        if (t < cnt) {
            const int i = base + t;
            int s = (i < deg) ? col[start + i] : n;
            s = min(max(s, 0), NNODES - 1);
            s_lds[t] = s;
#pragma unroll
            for (int hh = 0; hh < H; hh++) {
                float e = asrc[(long)s * H + hh] + ad_loc[hh];
                e = (e > 0.f) ? e : 0.2f * e;
                e = fminf(fmaxf(e, -60.f), 60.f);
                w_lds[hh][t] = __expf(e);
            }
        }
        __syncthreads();
#pragma unroll 4
        for (int i = 0; i < cnt; i++) {
            const int s = s_lds[i];
            const float wv = w_lds[myhead][i];
            if (CPT == 2) {
                const bf16x2 hv = *(const bf16x2*)(h + (long)s * HC + t * 2);
                accv[0] += wv * (float)hv[0];
                accv[1] += wv * (float)hv[1];
            } else {
                accv[0] += wv * (float)h[(long)s * HC + t];
            }
        }
        __syncthreads();
    }

#pragma unroll
    for (int j = 0; j < CPT; j++) {
        const int c = t * CPT + j;
        float o = accv[j] * rz + (float)bias[c];
        if (relu) o = fmaxf(o, 0.f);
        const long idx = (long)n * HC + c;
        if (fp32out) ((float*)outv)[idx] = o;
        else ((bf16*)outv)[idx] = (bf16)o;
    }
}

// ============================================================================
// Output heads from d_out section 0 (dtype per flag); writes sections 1,2
// ============================================================================
__global__ __launch_bounds__(256) void heads_kernel(
    const void* __restrict__ hbase, void* __restrict__ outv,
    const bf16* __restrict__ Wv, const bf16* __restrict__ bv,
    const bf16* __restrict__ Wt, const bf16* __restrict__ bt,
    const int* __restrict__ dflag, int N)
{
    const int fp32 = *dflag;
    __shared__ float hbuf[32][128];
    const int n0 = blockIdx.x * 32, t = threadIdx.x;
    for (int i = t; i < 32 * 128; i += 256) {
        const int node = n0 + (i >> 7), c = i & 127;
        float v = 0.f;
        if (node < N)
            v = fp32 ? ((const float*)hbase)[(long)node * 128 + c]
                     : (float)((const bf16*)hbase)[(long)node * 128 + c];
        hbuf[i >> 7][c] = v;
    }
    __syncthreads();
    const int m = t & 127;
    const bool vis = t < 128;
    const bf16* W = vis ? Wv : Wt;
    const float b = (float)(vis ? bv[m] : bt[m]);
    float acc[32];
#pragma unroll
    for (int i = 0; i < 32; i++) acc[i] = 0.f;
    for (int k0 = 0; k0 < 128; k0 += 8) {
        const bf16x8 wv8 = *(const bf16x8*)&W[m * 128 + k0];
#pragma unroll
        for (int kk = 0; kk < 8; kk++) {
            const float wk = (float)wv8[kk];
#pragma unroll
            for (int i = 0; i < 32; i++) acc[i] += hbuf[i][k0 + kk] * wk;
        }
    }
    const long sec = vis ? (long)N * 128 : (long)2 * N * 128;
#pragma unroll
    for (int i = 0; i < 32; i++) {
        const int node = n0 + i;
        if (node < N) {
            float o = fmaxf(acc[i] + b, 0.f);
            const long idx = sec + (long)node * 128 + m;
            if (fp32) ((float*)outv)[idx] = o;
            else ((bf16*)outv)[idx] = (bf16)o;
        }
    }
}

// ============================================================================
extern "C" void kernel_launch(void* const* d_in, const int* in_sizes, int n_in,
                              void* d_out, int out_size, void* d_ws, size_t ws_size,
                              hipStream_t stream)
{
    const int N = NNODES, E = NEDGES;
    const int* srcp = (const int*)d_in[1];
    const int* dstp = srcp + E;

    char* p0 = (char*)d_ws;
    char* p = p0;
    auto bump = [&](size_t b) { char* r = p; p += (b + 255) & ~(size_t)255; return r; };
    int*   dflag  = (int*)bump(256);
    bf16*  xc     = (bf16*)bump((size_t)N * 512 * 2);
    bf16*  W0c    = (bf16*)bump(262144 * 2);
    bf16*  as0c   = (bf16*)bump(512 * 2);
    bf16*  ad0c   = (bf16*)bump(512 * 2);
    bf16*  b0c    = (bf16*)bump(512 * 2);
    bf16*  W1c    = (bf16*)bump(262144 * 2);
    bf16*  as1c   = (bf16*)bump(512 * 2);
    bf16*  ad1c   = (bf16*)bump(512 * 2);
    bf16*  b1c    = (bf16*)bump(512 * 2);
    bf16*  W2c    = (bf16*)bump(65536 * 2);
    bf16*  as2c   = (bf16*)bump(128 * 2);
    bf16*  ad2c   = (bf16*)bump(128 * 2);
    bf16*  b2c    = (bf16*)bump(128 * 2);
    bf16*  Wvc    = (bf16*)bump(16384 * 2);
    bf16*  bvc    = (bf16*)bump(128 * 2);
    bf16*  Wtc    = (bf16*)bump(16384 * 2);
    bf16*  btc    = (bf16*)bump(128 * 2);
    int*   cnt    = (int*)bump((size_t)N * 4);
    int*   offs   = (int*)bump((size_t)N * 4);
    int*   rowptr = (int*)bump((size_t)(N + 1) * 4);
    int*   colarr = (int*)bump((size_t)E * 4);
    float* alphaS = (float*)bump((size_t)N * 4 * 4);
    float* alphaD = (float*)bump((size_t)N * 4 * 4);
    bf16*  bufA   = (bf16*)bump((size_t)N * 512 * 2);
    bf16*  bufB   = (bf16*)bump((size_t)N * 512 * 2);
    const size_t need = (size_t)(p - p0);

    detect_kernel<<<1, 64, 0, stream>>>((const unsigned int*)d_in[0], dflag);

    if (need > ws_size) {  // diagnostic fallback: zero output
        zero_out_kernel<<<((long)out_size + 255) / 256, 256, 0, stream>>>(d_out, out_size, dflag);
        return;
    }

    // convert all float tensors to bf16 working copies
    convert_kernel<<<(N * 512 + 255) / 256, 256, 0, stream>>>(d_in[0], xc, N * 512, dflag);
    CvtBatch cb;
    const void* ins[16] = {d_in[2], d_in[3], d_in[4], d_in[5], d_in[6], d_in[7], d_in[8], d_in[9],
                           d_in[10], d_in[11], d_in[12], d_in[13], d_in[14], d_in[15], d_in[16], d_in[17]};
    bf16* outs[16] = {W0c, as0c, ad0c, b0c, W1c, as1c, ad1c, b1c,
                      W2c, as2c, ad2c, b2c, Wvc, bvc, Wtc, btc};
    const int ns[16] = {262144, 512, 512, 512, 262144, 512, 512, 512,
                        65536, 128, 128, 128, 16384, 128, 16384, 128};
    for (int i = 0; i < 16; i++) { cb.in[i] = ins[i]; cb.out[i] = outs[i]; cb.n[i] = ns[i]; }
    convert_batch_kernel<<<dim3(256, 16), 256, 0, stream>>>(cb, dflag);

    // CSR by destination
    hipMemsetAsync(cnt, 0, (size_t)N * 4, stream);
    hipMemsetAsync(offs, 0, (size_t)N * 4, stream);
    hist_kernel<<<(E + 255) / 256, 256, 0, stream>>>(dstp, cnt, E);
    scan_kernel<<<1, 1024, 0, stream>>>(cnt, rowptr, N);
    fill_kernel<<<(E + 255) / 256, 256, 0, stream>>>(srcp, dstp, rowptr, offs, colarr, E);

    // Layer 0
    dim3 g0((N + 127) / 128, 4);
    gemm_bt<<<g0, 256, 0, stream>>>(xc, W0c, bufA, N, 512, 512);
    alpha_kernel<4><<<N, 256, 0, stream>>>(bufA, as0c, ad0c, alphaS, alphaD);
    agg_kernel<4, 256, 2><<<N, 256, 0, stream>>>(bufA, alphaS, alphaD, rowptr, colarr, b0c, bufB, nullptr, 1);

    // Layer 1
    gemm_bt<<<g0, 256, 0, stream>>>(bufB, W1c, bufA, N, 512, 512);
    alpha_kernel<4><<<N, 256, 0, stream>>>(bufA, as1c, ad1c, alphaS, alphaD);
    agg_kernel<4, 256, 2><<<N, 256, 0, stream>>>(bufA, alphaS, alphaD, rowptr, colarr, b1c, bufB, nullptr, 1);

    // Layer 2 (heads=1) -> d_out section 0 (dtype per flag)
    dim3 g2((N + 127) / 128, 1);
    gemm_bt<<<g2, 256, 0, stream>>>(bufB, W2c, bufA, N, 128, 512);
    alpha_kernel<1><<<N, 64, 0, stream>>>(bufA, as2c, ad2c, alphaS, alphaD);
    agg_kernel<1, 128, 1><<<N, 128, 0, stream>>>(bufA, alphaS, alphaD, rowptr, colarr, b2c, d_out, dflag, 0);

    // Output heads -> sections 1,2
    heads_kernel<<<(N + 31) / 32, 256, 0, stream>>>(d_out, d_out, Wvc, bvc, Wtc, btc, dflag, N);
}

// Round 3
// 944.532 us; speedup vs baseline: 1.1013x; 1.1013x over previous
//
#include <hip/hip_runtime.h>
#include <hip/hip_bf16.h>
#include <math.h>

typedef __bf16 bf16;
typedef __bf16 bf16x2 __attribute__((ext_vector_type(2)));
typedef __bf16 bf16x8 __attribute__((ext_vector_type(8)));
typedef float f32x4 __attribute__((ext_vector_type(4)));

#define NNODES 50000
#define NEDGES 800000

// ---- async global->LDS, 16B per lane (lane-contiguous LDS dest required) ----
static __device__ __forceinline__ void gld_lds16(const void* g, void* l) {
    __builtin_amdgcn_global_load_lds((__attribute__((address_space(1))) void*)g,
                                     (__attribute__((address_space(3))) void*)l,
                                     16, 0, 0);
}

// ============================================================================
// dtype detect (flag=1 -> inputs are fp32), verified working in round 2
// ============================================================================
__global__ void detect_kernel(const unsigned int* __restrict__ xw, int* __restrict__ flag)
{
    const int l = threadIdx.x;  // 64 threads
    int c = 0;
    for (int i = l; i < 4096; i += 64) {
        const unsigned int b1 = (xw[i] >> 8) & 0x7Fu;
        c += (b1 >= 0x34u && b1 <= 0x43u) ? 1 : 0;
    }
#pragma unroll
    for (int off = 32; off; off >>= 1) c += __shfl_xor(c, off);
    if (l == 0) *flag = (c < 2048) ? 1 : 0;
}

__global__ __launch_bounds__(256) void zero_out_kernel(void* out, long n, const int* __restrict__ flag)
{
    const int fp32 = *flag;
    const long i = (long)blockIdx.x * 256 + threadIdx.x;
    if (i < n) {
        if (fp32) ((float*)out)[i] = 0.f;
        else ((bf16*)out)[i] = (bf16)0.f;
    }
}

// ============================================================================
// converts: produce bf16 working copies regardless of input dtype
// ============================================================================
__global__ __launch_bounds__(256) void convert_kernel(
    const void* __restrict__ in, bf16* __restrict__ out, int n, const int* __restrict__ flag)
{
    const int fp32 = *flag;
    const int i = blockIdx.x * 256 + threadIdx.x;
    if (i >= n) return;
    out[i] = fp32 ? (bf16)(((const float*)in)[i]) : ((const bf16*)in)[i];
}

struct CvtBatch { const void* in[16]; bf16* out[16]; int n[16]; };

__global__ __launch_bounds__(256) void convert_batch_kernel(CvtBatch b, const int* __restrict__ flag)
{
    const int fp32 = *flag;
    const int it = blockIdx.y;
    const int n = b.n[it];
    const void* in = b.in[it];
    bf16* out = b.out[it];
    for (int i = blockIdx.x * 256 + threadIdx.x; i < n; i += gridDim.x * 256)
        out[i] = fp32 ? (bf16)(((const float*)in)[i]) : ((const bf16*)in)[i];
}

// ============================================================================
// GEMM: C[M,N] = A[M,K] * B[N,K]^T  (bf16 in/out, fp32 acc), 128x128 tile,
// BK=32, 4 waves 2x2, 4x4 of mfma 16x16x32. m97 async global_load_lds
// staging (LDS byte layout identical to the round-2-verified sync version:
// thread t -> As[t*16B..+16B], i.e. wave-uniform base + lane*16).
// ============================================================================
__global__ __launch_bounds__(256) void gemm_bt(
    const bf16* __restrict__ A, const bf16* __restrict__ B,
    bf16* __restrict__ C, int M, int N, int K)
{
    __shared__ __align__(16) bf16 As[128 * 32];
    __shared__ __align__(16) bf16 Bs[128 * 32];
    const int tid  = threadIdx.x;
    const int lane = tid & 63;
    const int w    = tid >> 6;
    const int wm   = (w >> 1) * 64, wn = (w & 1) * 64;
    const int mBase = blockIdx.x * 128, nBase = blockIdx.y * 128;

    f32x4 acc[4][4];
#pragma unroll
    for (int i = 0; i < 4; i++)
#pragma unroll
        for (int j = 0; j < 4; j++)
#pragma unroll
            for (int r = 0; r < 4; r++) acc[i][j][r] = 0.f;

    const int rA   = tid >> 2;
    const int kseg = (tid & 3) * 8;
    int ra0 = mBase + rA;       if (ra0 > M - 1) ra0 = M - 1;
    int ra1 = mBase + rA + 64;  if (ra1 > M - 1) ra1 = M - 1;
    const bf16* gA0 = A + (long)ra0 * K + kseg;
    const bf16* gA1 = A + (long)ra1 * K + kseg;
    const bf16* gB0 = B + (long)(nBase + rA) * K + kseg;
    const bf16* gB1 = B + (long)(nBase + rA + 64) * K + kseg;
    bf16* lA0 = &As[tid * 8];
    bf16* lA1 = &As[(tid + 256) * 8];
    bf16* lB0 = &Bs[tid * 8];
    bf16* lB1 = &Bs[(tid + 256) * 8];

    const int quad = lane >> 4, l16 = lane & 15;

    for (int k0 = 0; k0 < K; k0 += 32) {
        gld_lds16(gA0 + k0, lA0);
        gld_lds16(gA1 + k0, lA1);
        gld_lds16(gB0 + k0, lB0);
        gld_lds16(gB1 + k0, lB1);
        __syncthreads();           // drains vmcnt: staging visible
        bf16x8 af[4], bfr[4];
#pragma unroll
        for (int i = 0; i < 4; i++) {
            af[i]  = *(const bf16x8*)&As[(wm + i * 16 + l16) * 32 + quad * 8];
            bfr[i] = *(const bf16x8*)&Bs[(wn + i * 16 + l16) * 32 + quad * 8];
        }
#pragma unroll
        for (int i = 0; i < 4; i++)
#pragma unroll
            for (int j = 0; j < 4; j++)
                acc[i][j] = __builtin_amdgcn_mfma_f32_16x16x32_bf16(af[i], bfr[j], acc[i][j], 0, 0, 0);
        __syncthreads();           // all reads done before next staging
    }

    // C/D layout: col = lane&15, row = (lane>>4)*4 + r  [m89/m91 verified]
#pragma unroll
    for (int i = 0; i < 4; i++) {
        const int row0 = mBase + wm + i * 16 + quad * 4;
#pragma unroll
        for (int j = 0; j < 4; j++) {
            const int colg = nBase + wn + j * 16 + l16;
#pragma unroll
            for (int r = 0; r < 4; r++) {
                const int row = row0 + r;
                if (row < M) C[(long)row * N + colg] = (bf16)acc[i][j][r];
            }
        }
    }
}

// ============================================================================
// alpha[n,h] = sum_c h[n,h,c]*a[h,c]  (fp32 out); one node/block, wave/head
// ============================================================================
template <int H>
__global__ __launch_bounds__(H * 64) void alpha_kernel(
    const bf16* __restrict__ h, const bf16* __restrict__ av,
    const bf16* __restrict__ dv, float* __restrict__ as_out,
    float* __restrict__ ad_out)
{
    const int C = 128, HC = H * C;
    const int n = blockIdx.x;
    const int t = threadIdx.x;
    const int ht = t >> 6, l = t & 63;
    const bf16* hr = h + (long)n * HC + ht * C;
    float ps = 0.f, pd = 0.f;
#pragma unroll
    for (int c0 = 0; c0 < C; c0 += 64) {
        const float hv = (float)hr[c0 + l];
        ps += hv * (float)av[ht * C + c0 + l];
        pd += hv * (float)dv[ht * C + c0 + l];
    }
#pragma unroll
    for (int off = 32; off; off >>= 1) {
        ps += __shfl_xor(ps, off);
        pd += __shfl_xor(pd, off);
    }
    if (l == 0) {
        as_out[(long)n * H + ht] = ps;
        ad_out[(long)n * H + ht] = pd;
    }
}

// ============================================================================
// CSR build: histogram -> hierarchical scan (3 kernels) -> fill
// ============================================================================
__global__ void hist_kernel(const int* __restrict__ dst, int* __restrict__ cnt, int E)
{
    const int e = blockIdx.x * blockDim.x + threadIdx.x;
    if (e < E) atomicAdd(&cnt[dst[e]], 1);
}

__global__ __launch_bounds__(256) void scan1_kernel(
    const int* __restrict__ cnt, int* __restrict__ rowptr, int* __restrict__ blksum, int n)
{
    __shared__ int buf[256];
    const int b = blockIdx.x, t = threadIdx.x, i = b * 256 + t;
    const int v = (i < n) ? cnt[i] : 0;
    buf[t] = v;
    __syncthreads();
    for (int off = 1; off < 256; off <<= 1) {
        const int add = (t >= off) ? buf[t - off] : 0;
        __syncthreads();
        buf[t] += add;
        __syncthreads();
    }
    if (i < n) rowptr[i + 1] = buf[t];
    if (t == 255) blksum[b] = buf[255];
    if (b == 0 && t == 0) rowptr[0] = 0;
}

__global__ __launch_bounds__(256) void scan2_kernel(int* __restrict__ blksum, int nb)
{
    __shared__ int buf[256];
    const int t = threadIdx.x;
    const int v = (t < nb) ? blksum[t] : 0;
    buf[t] = v;
    __syncthreads();
    for (int off = 1; off < 256; off <<= 1) {
        const int add = (t >= off) ? buf[t - off] : 0;
        __syncthreads();
        buf[t] += add;
        __syncthreads();
    }
    if (t < nb) blksum[t] = buf[t] - v;   // exclusive block offset
}

__global__ __launch_bounds__(256) void scan3_kernel(
    int* __restrict__ rowptr, const int* __restrict__ blksum, int n)
{
    const int b = blockIdx.x, i = b * 256 + threadIdx.x;
    if (i < n) rowptr[i + 1] += blksum[b];
}

__global__ void fill_kernel(const int* __restrict__ src, const int* __restrict__ dst,
                            const int* __restrict__ rowptr, int* __restrict__ off,
                            int* __restrict__ col, int E)
{
    const int e = blockIdx.x * blockDim.x + threadIdx.x;
    if (e < E) {
        const int d = dst[e];
        const int p = rowptr[d] + atomicAdd(&off[d], 1);
        col[p] = src[e];
    }
}

// ============================================================================
// GAT aggregation: WAVE-PER-NODE (4 nodes/block), no LDS, no barriers.
// Lane owns VPL = H*128/64 channels -> 16B (H=4) / 4B (H=1) coalesced gathers.
// Exact two-pass softmax: pass1 z via 16-lane-group (H=4) / full-wave (H=1)
// shuffle reduce; pass2 recomputes the weight in-register per edge.
// ============================================================================
template <int H>
__global__ __launch_bounds__(256) void agg_kernel(
    const bf16* __restrict__ h, const float* __restrict__ asrc,
    const float* __restrict__ adst, const int* __restrict__ rowptr,
    const int* __restrict__ col, const bf16* __restrict__ bias,
    void* __restrict__ outv, const int* __restrict__ dflag, int relu)
{
    constexpr int HC  = H * 128;
    constexpr int VPL = HC / 64;              // channels per lane
    typedef __bf16 vec_t __attribute__((ext_vector_type(VPL)));
    const int w = threadIdx.x >> 6, lane = threadIdx.x & 63;
    const int n = blockIdx.x * 4 + w;
    if (n >= NNODES) return;
    const int fp32out = dflag ? *dflag : 0;
    const int hol = (lane * VPL) >> 7;        // head of this lane's channels
    const float ad = adst[(long)n * H + hol];
    const int start = rowptr[n];
    const int deg   = rowptr[n + 1] - start;
    const int total = deg + 1;                // + virtual self-loop

    // pass 1: z per head
    float z = 0.f;
    {
        const int i0 = (H == 4) ? (lane & 15) : lane;
        const int st = (H == 4) ? 16 : 64;
        for (int i = i0; i < total; i += st) {
            const int s = (i < deg) ? col[start + i] : n;
            float e = asrc[(long)s * H + hol] + ad;
            e = (e > 0.f) ? e : 0.2f * e;
            e = fminf(fmaxf(e, -60.f), 60.f);
            z += __expf(e);
        }
    }
    if (H == 4) {
#pragma unroll
        for (int off = 8; off; off >>= 1) z += __shfl_xor(z, off);  // within 16-lane group
    } else {
#pragma unroll
        for (int off = 32; off; off >>= 1) z += __shfl_xor(z, off); // full wave
    }

    // pass 2: weighted gather-accumulate
    float accv[VPL];
#pragma unroll
    for (int j = 0; j < VPL; j++) accv[j] = 0.f;
    const bf16* hp = h + (long)lane * VPL;
#pragma unroll 2
    for (int i = 0; i < total; i++) {
        const int s = (i < deg) ? col[start + i] : n;
        float e = asrc[(long)s * H + hol] + ad;
        e = (e > 0.f) ? e : 0.2f * e;
        e = fminf(fmaxf(e, -60.f), 60.f);
        const float wv = __expf(e);
        const vec_t hv = *(const vec_t*)(hp + (long)s * HC);
#pragma unroll
        for (int j = 0; j < VPL; j++) accv[j] += wv * (float)hv[j];
    }

    const float rz = 1.f / (z + 1e-16f);
    const long obase = (long)n * HC + lane * VPL;
    if (fp32out) {
        float* op = (float*)outv;
#pragma unroll
        for (int j = 0; j < VPL; j++) {
            float o = accv[j] * rz + (float)bias[lane * VPL + j];
            if (relu) o = fmaxf(o, 0.f);
            op[obase + j] = o;
        }
    } else {
        vec_t ov;
#pragma unroll
        for (int j = 0; j < VPL; j++) {
            float o = accv[j] * rz + (float)bias[lane * VPL + j];
            if (relu) o = fmaxf(o, 0.f);
            ov[j] = (bf16)o;
        }
        *(vec_t*)((bf16*)outv + obase) = ov;
    }
}

// ============================================================================
// Output heads from d_out section 0 (dtype per flag); writes sections 1,2
// ============================================================================
__global__ __launch_bounds__(256) void heads_kernel(
    const void* __restrict__ hbase, void* __restrict__ outv,
    const bf16* __restrict__ Wv, const bf16* __restrict__ bv,
    const bf16* __restrict__ Wt, const bf16* __restrict__ bt,
    const int* __restrict__ dflag, int N)
{
    const int fp32 = *dflag;
    __shared__ float hbuf[32][128];
    const int n0 = blockIdx.x * 32, t = threadIdx.x;
    for (int i = t; i < 32 * 128; i += 256) {
        const int node = n0 + (i >> 7), c = i & 127;
        float v = 0.f;
        if (node < N)
            v = fp32 ? ((const float*)hbase)[(long)node * 128 + c]
                     : (float)((const bf16*)hbase)[(long)node * 128 + c];
        hbuf[i >> 7][c] = v;
    }
    __syncthreads();
    const int m = t & 127;
    const bool vis = t < 128;
    const bf16* W = vis ? Wv : Wt;
    const float b = (float)(vis ? bv[m] : bt[m]);
    float acc[32];
#pragma unroll
    for (int i = 0; i < 32; i++) acc[i] = 0.f;
    for (int k0 = 0; k0 < 128; k0 += 8) {
        const bf16x8 wv8 = *(const bf16x8*)&W[m * 128 + k0];
#pragma unroll
        for (int kk = 0; kk < 8; kk++) {
            const float wk = (float)wv8[kk];
#pragma unroll
            for (int i = 0; i < 32; i++) acc[i] += hbuf[i][k0 + kk] * wk;
        }
    }
    const long sec = vis ? (long)N * 128 : (long)2 * N * 128;
#pragma unroll
    for (int i = 0; i < 32; i++) {
        const int node = n0 + i;
        if (node < N) {
            float o = fmaxf(acc[i] + b, 0.f);
            const long idx = sec + (long)node * 128 + m;
            if (fp32) ((float*)outv)[idx] = o;
            else ((bf16*)outv)[idx] = (bf16)o;
        }
    }
}

// ============================================================================
extern "C" void kernel_launch(void* const* d_in, const int* in_sizes, int n_in,
                              void* d_out, int out_size, void* d_ws, size_t ws_size,
                              hipStream_t stream)
{
    const int N = NNODES, E = NEDGES;
    const int* srcp = (const int*)d_in[1];
    const int* dstp = srcp + E;

    char* p0 = (char*)d_ws;
    char* p = p0;
    auto bump = [&](size_t b) { char* r = p; p += (b + 255) & ~(size_t)255; return r; };
    int*   dflag  = (int*)bump(256);
    bf16*  xc     = (bf16*)bump((size_t)N * 512 * 2);
    bf16*  W0c    = (bf16*)bump(262144 * 2);
    bf16*  as0c   = (bf16*)bump(512 * 2);
    bf16*  ad0c   = (bf16*)bump(512 * 2);
    bf16*  b0c    = (bf16*)bump(512 * 2);
    bf16*  W1c    = (bf16*)bump(262144 * 2);
    bf16*  as1c   = (bf16*)bump(512 * 2);
    bf16*  ad1c   = (bf16*)bump(512 * 2);
    bf16*  b1c    = (bf16*)bump(512 * 2);
    bf16*  W2c    = (bf16*)bump(65536 * 2);
    bf16*  as2c   = (bf16*)bump(128 * 2);
    bf16*  ad2c   = (bf16*)bump(128 * 2);
    bf16*  b2c    = (bf16*)bump(128 * 2);
    bf16*  Wvc    = (bf16*)bump(16384 * 2);
    bf16*  bvc    = (bf16*)bump(128 * 2);
    bf16*  Wtc    = (bf16*)bump(16384 * 2);
    bf16*  btc    = (bf16*)bump(128 * 2);
    int*   cnt    = (int*)bump((size_t)N * 4);
    int*   offs   = (int*)bump((size_t)N * 4);
    int*   rowptr = (int*)bump((size_t)(N + 1) * 4);
    int*   blksum = (int*)bump(256 * 4);
    int*   colarr = (int*)bump((size_t)E * 4);
    float* alphaS = (float*)bump((size_t)N * 4 * 4);
    float* alphaD = (float*)bump((size_t)N * 4 * 4);
    bf16*  bufA   = (bf16*)bump((size_t)N * 512 * 2);
    bf16*  bufB   = (bf16*)bump((size_t)N * 512 * 2);
    const size_t need = (size_t)(p - p0);

    detect_kernel<<<1, 64, 0, stream>>>((const unsigned int*)d_in[0], dflag);

    if (need > ws_size) {  // diagnostic fallback: zero output
        zero_out_kernel<<<((long)out_size + 255) / 256, 256, 0, stream>>>(d_out, out_size, dflag);
        return;
    }

    // convert all float tensors to bf16 working copies
    convert_kernel<<<(N * 512 + 255) / 256, 256, 0, stream>>>(d_in[0], xc, N * 512, dflag);
    CvtBatch cb;
    const void* ins[16] = {d_in[2], d_in[3], d_in[4], d_in[5], d_in[6], d_in[7], d_in[8], d_in[9],
                           d_in[10], d_in[11], d_in[12], d_in[13], d_in[14], d_in[15], d_in[16], d_in[17]};
    bf16* outs[16] = {W0c, as0c, ad0c, b0c, W1c, as1c, ad1c, b1c,
                      W2c, as2c, ad2c, b2c, Wvc, bvc, Wtc, btc};
    const int ns[16] = {262144, 512, 512, 512, 262144, 512, 512, 512,
                        65536, 128, 128, 128, 16384, 128, 16384, 128};
    for (int i = 0; i < 16; i++) { cb.in[i] = ins[i]; cb.out[i] = outs[i]; cb.n[i] = ns[i]; }
    convert_batch_kernel<<<dim3(256, 16), 256, 0, stream>>>(cb, dflag);

    // CSR by destination
    const int nb = (N + 255) / 256;  // 196
    hipMemsetAsync(cnt, 0, (size_t)N * 4, stream);
    hipMemsetAsync(offs, 0, (size_t)N * 4, stream);
    hist_kernel<<<(E + 255) / 256, 256, 0, stream>>>(dstp, cnt, E);
    scan1_kernel<<<nb, 256, 0, stream>>>(cnt, rowptr, blksum, N);
    scan2_kernel<<<1, 256, 0, stream>>>(blksum, nb);
    scan3_kernel<<<nb, 256, 0, stream>>>(rowptr, blksum, N);
    fill_kernel<<<(E + 255) / 256, 256, 0, stream>>>(srcp, dstp, rowptr, offs, colarr, E);

    const int gagg = (N + 3) / 4;  // 12500 blocks, 4 nodes each

    // Layer 0
    dim3 g0((N + 127) / 128, 4);
    gemm_bt<<<g0, 256, 0, stream>>>(xc, W0c, bufA, N, 512, 512);
    alpha_kernel<4><<<N, 256, 0, stream>>>(bufA, as0c, ad0c, alphaS, alphaD);
    agg_kernel<4><<<gagg, 256, 0, stream>>>(bufA, alphaS, alphaD, rowptr, colarr, b0c, bufB, nullptr, 1);

    // Layer 1
    gemm_bt<<<g0, 256, 0, stream>>>(bufB, W1c, bufA, N, 512, 512);
    alpha_kernel<4><<<N, 256, 0, stream>>>(bufA, as1c, ad1c, alphaS, alphaD);
    agg_kernel<4><<<gagg, 256, 0, stream>>>(bufA, alphaS, alphaD, rowptr, colarr, b1c, bufB, nullptr, 1);

    // Layer 2 (heads=1) -> d_out section 0 (dtype per flag)
    dim3 g2((N + 127) / 128, 1);
    gemm_bt<<<g2, 256, 0, stream>>>(bufB, W2c, bufA, N, 128, 512);
    alpha_kernel<1><<<N, 64, 0, stream>>>(bufA, as2c, ad2c, alphaS, alphaD);
    agg_kernel<1><<<gagg, 256, 0, stream>>>(bufA, alphaS, alphaD, rowptr, colarr, b2c, d_out, dflag, 0);

    // Output heads -> sections 1,2
    heads_kernel<<<(N + 31) / 32, 256, 0, stream>>>(d_out, d_out, Wvc, bvc, Wtc, btc, dflag, N);
}

// Round 4
// 894.055 us; speedup vs baseline: 1.1635x; 1.0565x over previous
//
#include <hip/hip_runtime.h>
#include <hip/hip_bf16.h>
#include <math.h>

typedef __bf16 bf16;
typedef __bf16 bf16x2 __attribute__((ext_vector_type(2)));
typedef __bf16 bf16x8 __attribute__((ext_vector_type(8)));
typedef float f32x4 __attribute__((ext_vector_type(4)));

#define NNODES 50000
#define NEDGES 800000

// ---- async global->LDS, 16B per lane (lane-contiguous LDS dest required) ----
static __device__ __forceinline__ void gld_lds16(const void* g, void* l) {
    __builtin_amdgcn_global_load_lds((__attribute__((address_space(1))) void*)g,
                                     (__attribute__((address_space(3))) void*)l,
                                     16, 0, 0);
}

// ============================================================================
// dtype detect (flag=1 -> inputs are fp32), verified working in round 2
// ============================================================================
__global__ void detect_kernel(const unsigned int* __restrict__ xw, int* __restrict__ flag)
{
    const int l = threadIdx.x;  // 64 threads
    int c = 0;
    for (int i = l; i < 4096; i += 64) {
        const unsigned int b1 = (xw[i] >> 8) & 0x7Fu;
        c += (b1 >= 0x34u && b1 <= 0x43u) ? 1 : 0;
    }
#pragma unroll
    for (int off = 32; off; off >>= 1) c += __shfl_xor(c, off);
    if (l == 0) *flag = (c < 2048) ? 1 : 0;
}

__global__ __launch_bounds__(256) void zero_out_kernel(void* out, long n, const int* __restrict__ flag)
{
    const int fp32 = *flag;
    const long i = (long)blockIdx.x * 256 + threadIdx.x;
    if (i < n) {
        if (fp32) ((float*)out)[i] = 0.f;
        else ((bf16*)out)[i] = (bf16)0.f;
    }
}

// ============================================================================
// converts: produce bf16 working copies regardless of input dtype
// ============================================================================
__global__ __launch_bounds__(256) void convert_kernel(
    const void* __restrict__ in, bf16* __restrict__ out, int n, const int* __restrict__ flag)
{
    const int fp32 = *flag;
    const int i = blockIdx.x * 256 + threadIdx.x;
    if (i >= n) return;
    out[i] = fp32 ? (bf16)(((const float*)in)[i]) : ((const bf16*)in)[i];
}

struct CvtBatch { const void* in[16]; bf16* out[16]; int n[16]; };

__global__ __launch_bounds__(256) void convert_batch_kernel(CvtBatch b, const int* __restrict__ flag)
{
    const int fp32 = *flag;
    const int it = blockIdx.y;
    const int n = b.n[it];
    const void* in = b.in[it];
    bf16* out = b.out[it];
    for (int i = blockIdx.x * 256 + threadIdx.x; i < n; i += gridDim.x * 256)
        out[i] = fp32 ? (bf16)(((const float*)in)[i]) : ((const bf16*)in)[i];
}

// ============================================================================
// GEMM: C[M,N] = A[M,K] * B[N,K]^T  (bf16 in/out, fp32 acc), 128x128 tile,
// BK=32, 4 waves 2x2, 4x4 of mfma 16x16x32, m97 global_load_lds staging.
// ============================================================================
__global__ __launch_bounds__(256) void gemm_bt(
    const bf16* __restrict__ A, const bf16* __restrict__ B,
    bf16* __restrict__ C, int M, int N, int K)
{
    __shared__ __align__(16) bf16 As[128 * 32];
    __shared__ __align__(16) bf16 Bs[128 * 32];
    const int tid  = threadIdx.x;
    const int lane = tid & 63;
    const int w    = tid >> 6;
    const int wm   = (w >> 1) * 64, wn = (w & 1) * 64;
    const int mBase = blockIdx.x * 128, nBase = blockIdx.y * 128;

    f32x4 acc[4][4];
#pragma unroll
    for (int i = 0; i < 4; i++)
#pragma unroll
        for (int j = 0; j < 4; j++)
#pragma unroll
            for (int r = 0; r < 4; r++) acc[i][j][r] = 0.f;

    const int rA   = tid >> 2;
    const int kseg = (tid & 3) * 8;
    int ra0 = mBase + rA;       if (ra0 > M - 1) ra0 = M - 1;
    int ra1 = mBase + rA + 64;  if (ra1 > M - 1) ra1 = M - 1;
    const bf16* gA0 = A + (long)ra0 * K + kseg;
    const bf16* gA1 = A + (long)ra1 * K + kseg;
    const bf16* gB0 = B + (long)(nBase + rA) * K + kseg;
    const bf16* gB1 = B + (long)(nBase + rA + 64) * K + kseg;
    bf16* lA0 = &As[tid * 8];
    bf16* lA1 = &As[(tid + 256) * 8];
    bf16* lB0 = &Bs[tid * 8];
    bf16* lB1 = &Bs[(tid + 256) * 8];

    const int quad = lane >> 4, l16 = lane & 15;

    for (int k0 = 0; k0 < K; k0 += 32) {
        gld_lds16(gA0 + k0, lA0);
        gld_lds16(gA1 + k0, lA1);
        gld_lds16(gB0 + k0, lB0);
        gld_lds16(gB1 + k0, lB1);
        __syncthreads();
        bf16x8 af[4], bfr[4];
#pragma unroll
        for (int i = 0; i < 4; i++) {
            af[i]  = *(const bf16x8*)&As[(wm + i * 16 + l16) * 32 + quad * 8];
            bfr[i] = *(const bf16x8*)&Bs[(wn + i * 16 + l16) * 32 + quad * 8];
        }
#pragma unroll
        for (int i = 0; i < 4; i++)
#pragma unroll
            for (int j = 0; j < 4; j++)
                acc[i][j] = __builtin_amdgcn_mfma_f32_16x16x32_bf16(af[i], bfr[j], acc[i][j], 0, 0, 0);
        __syncthreads();
    }

    // C/D layout: col = lane&15, row = (lane>>4)*4 + r  [m89/m91 verified]
#pragma unroll
    for (int i = 0; i < 4; i++) {
        const int row0 = mBase + wm + i * 16 + quad * 4;
#pragma unroll
        for (int j = 0; j < 4; j++) {
            const int colg = nBase + wn + j * 16 + l16;
#pragma unroll
            for (int r = 0; r < 4; r++) {
                const int row = row0 + r;
                if (row < M) C[(long)row * N + colg] = (bf16)acc[i][j][r];
            }
        }
    }
}

// ============================================================================
// alpha[n,h] = sum_c h[n,h,c]*a[h,c]  (fp32 out); one node/block, wave/head
// vectorized: lane handles channels {2l, 2l+1} in one bf16x2 load
// ============================================================================
template <int H>
__global__ __launch_bounds__(H * 64) void alpha_kernel(
    const bf16* __restrict__ h, const bf16* __restrict__ av,
    const bf16* __restrict__ dv, float* __restrict__ as_out,
    float* __restrict__ ad_out)
{
    const int C = 128, HC = H * C;
    const int n = blockIdx.x;
    const int t = threadIdx.x;
    const int ht = t >> 6, l = t & 63;
    const bf16x2 hv = *(const bf16x2*)(h  + (long)n * HC + ht * C + 2 * l);
    const bf16x2 a2 = *(const bf16x2*)(av + ht * C + 2 * l);
    const bf16x2 d2 = *(const bf16x2*)(dv + ht * C + 2 * l);
    const float h0 = (float)hv[0], h1 = (float)hv[1];
    float ps = h0 * (float)a2[0] + h1 * (float)a2[1];
    float pd = h0 * (float)d2[0] + h1 * (float)d2[1];
#pragma unroll
    for (int off = 32; off; off >>= 1) {
        ps += __shfl_xor(ps, off);
        pd += __shfl_xor(pd, off);
    }
    if (l == 0) {
        as_out[(long)n * H + ht] = ps;
        ad_out[(long)n * H + ht] = pd;
    }
}

// ============================================================================
// CSR build: histogram -> hierarchical scan (3 kernels) -> fill
// ============================================================================
__global__ void hist_kernel(const int* __restrict__ dst, int* __restrict__ cnt, int E)
{
    const int e = blockIdx.x * blockDim.x + threadIdx.x;
    if (e < E) atomicAdd(&cnt[dst[e]], 1);
}

__global__ __launch_bounds__(256) void scan1_kernel(
    const int* __restrict__ cnt, int* __restrict__ rowptr, int* __restrict__ blksum, int n)
{
    __shared__ int buf[256];
    const int b = blockIdx.x, t = threadIdx.x, i = b * 256 + t;
    const int v = (i < n) ? cnt[i] : 0;
    buf[t] = v;
    __syncthreads();
    for (int off = 1; off < 256; off <<= 1) {
        const int add = (t >= off) ? buf[t - off] : 0;
        __syncthreads();
        buf[t] += add;
        __syncthreads();
    }
    if (i < n) rowptr[i + 1] = buf[t];
    if (t == 255) blksum[b] = buf[255];
    if (b == 0 && t == 0) rowptr[0] = 0;
}

__global__ __launch_bounds__(256) void scan2_kernel(int* __restrict__ blksum, int nb)
{
    __shared__ int buf[256];
    const int t = threadIdx.x;
    const int v = (t < nb) ? blksum[t] : 0;
    buf[t] = v;
    __syncthreads();
    for (int off = 1; off < 256; off <<= 1) {
        const int add = (t >= off) ? buf[t - off] : 0;
        __syncthreads();
        buf[t] += add;
        __syncthreads();
    }
    if (t < nb) blksum[t] = buf[t] - v;   // exclusive block offset
}

__global__ __launch_bounds__(256) void scan3_kernel(
    int* __restrict__ rowptr, const int* __restrict__ blksum, int n)
{
    const int b = blockIdx.x, i = b * 256 + threadIdx.x;
    if (i < n) rowptr[i + 1] += blksum[b];
}

__global__ void fill_kernel(const int* __restrict__ src, const int* __restrict__ dst,
                            const int* __restrict__ rowptr, int* __restrict__ off,
                            int* __restrict__ col, int E)
{
    const int e = blockIdx.x * blockDim.x + threadIdx.x;
    if (e < E) {
        const int d = dst[e];
        const int p = rowptr[d] + atomicAdd(&off[d], 1);
        col[p] = src[e];
    }
}

// ============================================================================
// GAT aggregation v3: wave-per-node, SINGLE PASS producer/consumer.
// Per 64-edge chunk: lane i is producer for edge i (1 coalesced col load,
// 1 asrc gather, H exps) -> stash (s, w[0..H)) in wave-private LDS slab.
// Consumer loop: broadcast ds_reads + one 16B row gather + VPL FMAs per edge;
// z accumulates alongside (exact: out = sum(w*h)/sum(w), e clamped to +-60).
// No __syncthreads (single-wave lockstep; wave_barrier pins compiler order).
// ============================================================================
template <int H>
__global__ __launch_bounds__(256) void agg_kernel(
    const bf16* __restrict__ h, const float* __restrict__ asrc,
    const float* __restrict__ adst, const int* __restrict__ rowptr,
    const int* __restrict__ col, const bf16* __restrict__ bias,
    void* __restrict__ outv, const int* __restrict__ dflag, int relu)
{
    constexpr int HC  = H * 128;
    constexpr int VPL = HC / 64;              // channels per lane
    typedef __bf16 vec_t __attribute__((ext_vector_type(VPL)));
    __shared__ float wt_s[4][64][H];
    __shared__ int   sv_s[4][64];
    const int w = threadIdx.x >> 6, lane = threadIdx.x & 63;
    const int n = blockIdx.x * 4 + w;
    if (n >= NNODES) return;
    const int fp32out = dflag ? *dflag : 0;
    const int hol = (lane * VPL) >> 7;        // head of this lane's channels

    float ad[H];
    if (H == 4) {
        const float4 d4 = *(const float4*)(adst + (long)n * 4);
        ad[0] = d4.x; ad[1] = d4.y; ad[2] = d4.z; ad[3] = d4.w;
    } else {
        ad[0] = adst[n];
    }
    const int start = rowptr[n];
    const int deg   = rowptr[n + 1] - start;
    const int total = deg + 1;                // + virtual self-loop

    float z = 0.f;
    float accv[VPL];
#pragma unroll
    for (int j = 0; j < VPL; j++) accv[j] = 0.f;
    const bf16* hp = h + (long)lane * VPL;

    for (int base = 0; base < total; base += 64) {
        // ---- producer: lane handles edge (base+lane) ----
        const int i = base + lane;
        const bool valid = i < total;
        const int s = (i < deg) ? col[start + i] : n;
        float wv[H];
        if (H == 4) {
            const float4 a4 = *(const float4*)(asrc + (long)s * 4);
            wv[0] = a4.x; wv[1] = a4.y; wv[2] = a4.z; wv[3] = a4.w;
        } else {
            wv[0] = asrc[s];
        }
#pragma unroll
        for (int hh = 0; hh < H; hh++) {
            float e = wv[hh] + ad[hh];
            e = (e > 0.f) ? e : 0.2f * e;
            e = fminf(fmaxf(e, -60.f), 60.f);
            wv[hh] = valid ? __expf(e) : 0.f;
        }
        sv_s[w][lane] = s;
#pragma unroll
        for (int hh = 0; hh < H; hh++) wt_s[w][lane][hh] = wv[hh];
        __builtin_amdgcn_wave_barrier();

        // ---- consumer: all lanes sweep the chunk ----
        const int cnt = min(64, total - base);
#pragma unroll 4
        for (int j = 0; j < cnt; j++) {
            const int ss = sv_s[w][j];           // broadcast read
            const float ww = wt_s[w][j][hol];    // broadcast per 16-group
            z += ww;
            const vec_t hv = *(const vec_t*)(hp + (long)ss * HC);
#pragma unroll
            for (int jj = 0; jj < VPL; jj++) accv[jj] += ww * (float)hv[jj];
        }
        __builtin_amdgcn_wave_barrier();
    }

    const float rz = 1.f / (z + 1e-16f);
    const long obase = (long)n * HC + lane * VPL;
    if (fp32out) {
        float* op = (float*)outv;
#pragma unroll
        for (int j = 0; j < VPL; j++) {
            float o = accv[j] * rz + (float)bias[lane * VPL + j];
            if (relu) o = fmaxf(o, 0.f);
            op[obase + j] = o;
        }
    } else {
        vec_t ov;
#pragma unroll
        for (int j = 0; j < VPL; j++) {
            float o = accv[j] * rz + (float)bias[lane * VPL + j];
            if (relu) o = fmaxf(o, 0.f);
            ov[j] = (bf16)o;
        }
        *(vec_t*)((bf16*)outv + obase) = ov;
    }
}

// ============================================================================
// Output heads from d_out section 0 (dtype per flag); writes sections 1,2
// ============================================================================
__global__ __launch_bounds__(256) void heads_kernel(
    const void* __restrict__ hbase, void* __restrict__ outv,
    const bf16* __restrict__ Wv, const bf16* __restrict__ bv,
    const bf16* __restrict__ Wt, const bf16* __restrict__ bt,
    const int* __restrict__ dflag, int N)
{
    const int fp32 = *dflag;
    __shared__ float hbuf[32][128];
    const int n0 = blockIdx.x * 32, t = threadIdx.x;
    for (int i = t; i < 32 * 128; i += 256) {
        const int node = n0 + (i >> 7), c = i & 127;
        float v = 0.f;
        if (node < N)
            v = fp32 ? ((const float*)hbase)[(long)node * 128 + c]
                     : (float)((const bf16*)hbase)[(long)node * 128 + c];
        hbuf[i >> 7][c] = v;
    }
    __syncthreads();
    const int m = t & 127;
    const bool vis = t < 128;
    const bf16* W = vis ? Wv : Wt;
    const float b = (float)(vis ? bv[m] : bt[m]);
    float acc[32];
#pragma unroll
    for (int i = 0; i < 32; i++) acc[i] = 0.f;
    for (int k0 = 0; k0 < 128; k0 += 8) {
        const bf16x8 wv8 = *(const bf16x8*)&W[m * 128 + k0];
#pragma unroll
        for (int kk = 0; kk < 8; kk++) {
            const float wk = (float)wv8[kk];
#pragma unroll
            for (int i = 0; i < 32; i++) acc[i] += hbuf[i][k0 + kk] * wk;
        }
    }
    const long sec = vis ? (long)N * 128 : (long)2 * N * 128;
#pragma unroll
    for (int i = 0; i < 32; i++) {
        const int node = n0 + i;
        if (node < N) {
            float o = fmaxf(acc[i] + b, 0.f);
            const long idx = sec + (long)node * 128 + m;
            if (fp32) ((float*)outv)[idx] = o;
            else ((bf16*)outv)[idx] = (bf16)o;
        }
    }
}

// ============================================================================
extern "C" void kernel_launch(void* const* d_in, const int* in_sizes, int n_in,
                              void* d_out, int out_size, void* d_ws, size_t ws_size,
                              hipStream_t stream)
{
    const int N = NNODES, E = NEDGES;
    const int* srcp = (const int*)d_in[1];
    const int* dstp = srcp + E;

    char* p0 = (char*)d_ws;
    char* p = p0;
    auto bump = [&](size_t b) { char* r = p; p += (b + 255) & ~(size_t)255; return r; };
    int*   dflag  = (int*)bump(256);
    bf16*  xc     = (bf16*)bump((size_t)N * 512 * 2);
    bf16*  W0c    = (bf16*)bump(262144 * 2);
    bf16*  as0c   = (bf16*)bump(512 * 2);
    bf16*  ad0c   = (bf16*)bump(512 * 2);
    bf16*  b0c    = (bf16*)bump(512 * 2);
    bf16*  W1c    = (bf16*)bump(262144 * 2);
    bf16*  as1c   = (bf16*)bump(512 * 2);
    bf16*  ad1c   = (bf16*)bump(512 * 2);
    bf16*  b1c    = (bf16*)bump(512 * 2);
    bf16*  W2c    = (bf16*)bump(65536 * 2);
    bf16*  as2c   = (bf16*)bump(128 * 2);
    bf16*  ad2c   = (bf16*)bump(128 * 2);
    bf16*  b2c    = (bf16*)bump(128 * 2);
    bf16*  Wvc    = (bf16*)bump(16384 * 2);
    bf16*  bvc    = (bf16*)bump(128 * 2);
    bf16*  Wtc    = (bf16*)bump(16384 * 2);
    bf16*  btc    = (bf16*)bump(128 * 2);
    int*   cnt    = (int*)bump((size_t)N * 4);
    int*   offs   = (int*)bump((size_t)N * 4);
    int*   rowptr = (int*)bump((size_t)(N + 1) * 4);
    int*   blksum = (int*)bump(256 * 4);
    int*   colarr = (int*)bump((size_t)E * 4);
    float* alphaS = (float*)bump((size_t)N * 4 * 4);
    float* alphaD = (float*)bump((size_t)N * 4 * 4);
    bf16*  bufA   = (bf16*)bump((size_t)N * 512 * 2);
    bf16*  bufB   = (bf16*)bump((size_t)N * 512 * 2);
    const size_t need = (size_t)(p - p0);

    detect_kernel<<<1, 64, 0, stream>>>((const unsigned int*)d_in[0], dflag);

    if (need > ws_size) {  // diagnostic fallback: zero output
        zero_out_kernel<<<((long)out_size + 255) / 256, 256, 0, stream>>>(d_out, out_size, dflag);
        return;
    }

    // convert all float tensors to bf16 working copies
    convert_kernel<<<(N * 512 + 255) / 256, 256, 0, stream>>>(d_in[0], xc, N * 512, dflag);
    CvtBatch cb;
    const void* ins[16] = {d_in[2], d_in[3], d_in[4], d_in[5], d_in[6], d_in[7], d_in[8], d_in[9],
                           d_in[10], d_in[11], d_in[12], d_in[13], d_in[14], d_in[15], d_in[16], d_in[17]};
    bf16* outs[16] = {W0c, as0c, ad0c, b0c, W1c, as1c, ad1c, b1c,
                      W2c, as2c, ad2c, b2c, Wvc, bvc, Wtc, btc};
    const int ns[16] = {262144, 512, 512, 512, 262144, 512, 512, 512,
                        65536, 128, 128, 128, 16384, 128, 16384, 128};
    for (int i = 0; i < 16; i++) { cb.in[i] = ins[i]; cb.out[i] = outs[i]; cb.n[i] = ns[i]; }
    convert_batch_kernel<<<dim3(256, 16), 256, 0, stream>>>(cb, dflag);

    // CSR by destination
    const int nb = (N + 255) / 256;  // 196
    hipMemsetAsync(cnt, 0, (size_t)N * 4, stream);
    hipMemsetAsync(offs, 0, (size_t)N * 4, stream);
    hist_kernel<<<(E + 255) / 256, 256, 0, stream>>>(dstp, cnt, E);
    scan1_kernel<<<nb, 256, 0, stream>>>(cnt, rowptr, blksum, N);
    scan2_kernel<<<1, 256, 0, stream>>>(blksum, nb);
    scan3_kernel<<<nb, 256, 0, stream>>>(rowptr, blksum, N);
    fill_kernel<<<(E + 255) / 256, 256, 0, stream>>>(srcp, dstp, rowptr, offs, colarr, E);

    const int gagg = (N + 3) / 4;  // 12500 blocks, 4 nodes each

    // Layer 0
    dim3 g0((N + 127) / 128, 4);
    gemm_bt<<<g0, 256, 0, stream>>>(xc, W0c, bufA, N, 512, 512);
    alpha_kernel<4><<<N, 256, 0, stream>>>(bufA, as0c, ad0c, alphaS, alphaD);
    agg_kernel<4><<<gagg, 256, 0, stream>>>(bufA, alphaS, alphaD, rowptr, colarr, b0c, bufB, nullptr, 1);

    // Layer 1
    gemm_bt<<<g0, 256, 0, stream>>>(bufB, W1c, bufA, N, 512, 512);
    alpha_kernel<4><<<N, 256, 0, stream>>>(bufA, as1c, ad1c, alphaS, alphaD);
    agg_kernel<4><<<gagg, 256, 0, stream>>>(bufA, alphaS, alphaD, rowptr, colarr, b1c, bufB, nullptr, 1);

    // Layer 2 (heads=1) -> d_out section 0 (dtype per flag)
    dim3 g2((N + 127) / 128, 1);
    gemm_bt<<<g2, 256, 0, stream>>>(bufB, W2c, bufA, N, 128, 512);
    alpha_kernel<1><<<N, 64, 0, stream>>>(bufA, as2c, ad2c, alphaS, alphaD);
    agg_kernel<1><<<gagg, 256, 0, stream>>>(bufA, alphaS, alphaD, rowptr, colarr, b2c, d_out, dflag, 0);

    // Output heads -> sections 1,2
    heads_kernel<<<(N + 31) / 32, 256, 0, stream>>>(d_out, d_out, Wvc, bvc, Wtc, btc, dflag, N);
}

// Round 5
// 892.552 us; speedup vs baseline: 1.1654x; 1.0017x over previous
//
#include <hip/hip_runtime.h>
#include <hip/hip_bf16.h>
#include <math.h>

typedef __bf16 bf16;
typedef __bf16 bf16x2 __attribute__((ext_vector_type(2)));
typedef __bf16 bf16x8 __attribute__((ext_vector_type(8)));
typedef float f32x4 __attribute__((ext_vector_type(4)));

#define NNODES 50000
#define NEDGES 800000

// ---- async global->LDS, 16B per lane (lane-contiguous LDS dest required) ----
static __device__ __forceinline__ void gld_lds16(const void* g, void* l) {
    __builtin_amdgcn_global_load_lds((__attribute__((address_space(1))) void*)g,
                                     (__attribute__((address_space(3))) void*)l,
                                     16, 0, 0);
}

// ============================================================================
// dtype detect (flag=1 -> inputs are fp32), verified working in round 2
// ============================================================================
__global__ void detect_kernel(const unsigned int* __restrict__ xw, int* __restrict__ flag)
{
    const int l = threadIdx.x;  // 64 threads
    int c = 0;
    for (int i = l; i < 4096; i += 64) {
        const unsigned int b1 = (xw[i] >> 8) & 0x7Fu;
        c += (b1 >= 0x34u && b1 <= 0x43u) ? 1 : 0;
    }
#pragma unroll
    for (int off = 32; off; off >>= 1) c += __shfl_xor(c, off);
    if (l == 0) *flag = (c < 2048) ? 1 : 0;
}

__global__ __launch_bounds__(256) void zero_out_kernel(void* out, long n, const int* __restrict__ flag)
{
    const int fp32 = *flag;
    const long i = (long)blockIdx.x * 256 + threadIdx.x;
    if (i < n) {
        if (fp32) ((float*)out)[i] = 0.f;
        else ((bf16*)out)[i] = (bf16)0.f;
    }
}

// ============================================================================
// converts: produce bf16 working copies regardless of input dtype
// ============================================================================
__global__ __launch_bounds__(256) void convert_kernel(
    const void* __restrict__ in, bf16* __restrict__ out, int n, const int* __restrict__ flag)
{
    const int fp32 = *flag;
    const int i = blockIdx.x * 256 + threadIdx.x;
    if (i >= n) return;
    out[i] = fp32 ? (bf16)(((const float*)in)[i]) : ((const bf16*)in)[i];
}

struct CvtBatch { const void* in[16]; bf16* out[16]; int n[16]; };

__global__ __launch_bounds__(256) void convert_batch_kernel(CvtBatch b, const int* __restrict__ flag)
{
    const int fp32 = *flag;
    const int it = blockIdx.y;
    const int n = b.n[it];
    const void* in = b.in[it];
    bf16* out = b.out[it];
    for (int i = blockIdx.x * 256 + threadIdx.x; i < n; i += gridDim.x * 256)
        out[i] = fp32 ? (bf16)(((const float*)in)[i]) : ((const bf16*)in)[i];
}

// ============================================================================
// GEMM: C[M,N] = A[M,K] * B[N,K]^T  (bf16 in/out, fp32 acc), 128x128 tile,
// BK=32, 4 waves 2x2, 4x4 of mfma 16x16x32, m97 global_load_lds staging.
// Grid: x = N-tiles (small), y = M-tiles -> consecutive blocks share A-tile
// (A fetched ~once from HBM instead of gridDim.x times).
// ============================================================================
__global__ __launch_bounds__(256) void gemm_bt(
    const bf16* __restrict__ A, const bf16* __restrict__ B,
    bf16* __restrict__ C, int M, int N, int K)
{
    __shared__ __align__(16) bf16 As[128 * 32];
    __shared__ __align__(16) bf16 Bs[128 * 32];
    const int tid  = threadIdx.x;
    const int lane = tid & 63;
    const int w    = tid >> 6;
    const int wm   = (w >> 1) * 64, wn = (w & 1) * 64;
    const int mBase = blockIdx.y * 128, nBase = blockIdx.x * 128;

    f32x4 acc[4][4];
#pragma unroll
    for (int i = 0; i < 4; i++)
#pragma unroll
        for (int j = 0; j < 4; j++)
#pragma unroll
            for (int r = 0; r < 4; r++) acc[i][j][r] = 0.f;

    const int rA   = tid >> 2;
    const int kseg = (tid & 3) * 8;
    int ra0 = mBase + rA;       if (ra0 > M - 1) ra0 = M - 1;
    int ra1 = mBase + rA + 64;  if (ra1 > M - 1) ra1 = M - 1;
    const bf16* gA0 = A + (long)ra0 * K + kseg;
    const bf16* gA1 = A + (long)ra1 * K + kseg;
    const bf16* gB0 = B + (long)(nBase + rA) * K + kseg;
    const bf16* gB1 = B + (long)(nBase + rA + 64) * K + kseg;
    bf16* lA0 = &As[tid * 8];
    bf16* lA1 = &As[(tid + 256) * 8];
    bf16* lB0 = &Bs[tid * 8];
    bf16* lB1 = &Bs[(tid + 256) * 8];

    const int quad = lane >> 4, l16 = lane & 15;

    for (int k0 = 0; k0 < K; k0 += 32) {
        gld_lds16(gA0 + k0, lA0);
        gld_lds16(gA1 + k0, lA1);
        gld_lds16(gB0 + k0, lB0);
        gld_lds16(gB1 + k0, lB1);
        __syncthreads();
        bf16x8 af[4], bfr[4];
#pragma unroll
        for (int i = 0; i < 4; i++) {
            af[i]  = *(const bf16x8*)&As[(wm + i * 16 + l16) * 32 + quad * 8];
            bfr[i] = *(const bf16x8*)&Bs[(wn + i * 16 + l16) * 32 + quad * 8];
        }
#pragma unroll
        for (int i = 0; i < 4; i++)
#pragma unroll
            for (int j = 0; j < 4; j++)
                acc[i][j] = __builtin_amdgcn_mfma_f32_16x16x32_bf16(af[i], bfr[j], acc[i][j], 0, 0, 0);
        __syncthreads();
    }

    // C/D layout: col = lane&15, row = (lane>>4)*4 + r  [m89/m91 verified]
#pragma unroll
    for (int i = 0; i < 4; i++) {
        const int row0 = mBase + wm + i * 16 + quad * 4;
#pragma unroll
        for (int j = 0; j < 4; j++) {
            const int colg = nBase + wn + j * 16 + l16;
#pragma unroll
            for (int r = 0; r < 4; r++) {
                const int row = row0 + r;
                if (row < M) C[(long)row * N + colg] = (bf16)acc[i][j][r];
            }
        }
    }
}

// ============================================================================
// alpha[n,h] = sum_c h[n,h,c]*a[h,c]  (fp32 out); one node/block, wave/head
// ============================================================================
template <int H>
__global__ __launch_bounds__(H * 64) void alpha_kernel(
    const bf16* __restrict__ h, const bf16* __restrict__ av,
    const bf16* __restrict__ dv, float* __restrict__ as_out,
    float* __restrict__ ad_out)
{
    const int C = 128, HC = H * C;
    const int n = blockIdx.x;
    const int t = threadIdx.x;
    const int ht = t >> 6, l = t & 63;
    const bf16x2 hv = *(const bf16x2*)(h  + (long)n * HC + ht * C + 2 * l);
    const bf16x2 a2 = *(const bf16x2*)(av + ht * C + 2 * l);
    const bf16x2 d2 = *(const bf16x2*)(dv + ht * C + 2 * l);
    const float h0 = (float)hv[0], h1 = (float)hv[1];
    float ps = h0 * (float)a2[0] + h1 * (float)a2[1];
    float pd = h0 * (float)d2[0] + h1 * (float)d2[1];
#pragma unroll
    for (int off = 32; off; off >>= 1) {
        ps += __shfl_xor(ps, off);
        pd += __shfl_xor(pd, off);
    }
    if (l == 0) {
        as_out[(long)n * H + ht] = ps;
        ad_out[(long)n * H + ht] = pd;
    }
}

// ============================================================================
// CSR build: histogram -> hierarchical scan (3 kernels) -> fill
// ============================================================================
__global__ void hist_kernel(const int* __restrict__ dst, int* __restrict__ cnt, int E)
{
    const int e = blockIdx.x * blockDim.x + threadIdx.x;
    if (e < E) atomicAdd(&cnt[dst[e]], 1);
}

__global__ __launch_bounds__(256) void scan1_kernel(
    const int* __restrict__ cnt, int* __restrict__ rowptr, int* __restrict__ blksum, int n)
{
    __shared__ int buf[256];
    const int b = blockIdx.x, t = threadIdx.x, i = b * 256 + t;
    const int v = (i < n) ? cnt[i] : 0;
    buf[t] = v;
    __syncthreads();
    for (int off = 1; off < 256; off <<= 1) {
        const int add = (t >= off) ? buf[t - off] : 0;
        __syncthreads();
        buf[t] += add;
        __syncthreads();
    }
    if (i < n) rowptr[i + 1] = buf[t];
    if (t == 255) blksum[b] = buf[255];
    if (b == 0 && t == 0) rowptr[0] = 0;
}

__global__ __launch_bounds__(256) void scan2_kernel(int* __restrict__ blksum, int nb)
{
    __shared__ int buf[256];
    const int t = threadIdx.x;
    const int v = (t < nb) ? blksum[t] : 0;
    buf[t] = v;
    __syncthreads();
    for (int off = 1; off < 256; off <<= 1) {
        const int add = (t >= off) ? buf[t - off] : 0;
        __syncthreads();
        buf[t] += add;
        __syncthreads();
    }
    if (t < nb) blksum[t] = buf[t] - v;   // exclusive block offset
}

__global__ __launch_bounds__(256) void scan3_kernel(
    int* __restrict__ rowptr, const int* __restrict__ blksum, int n)
{
    const int b = blockIdx.x, i = b * 256 + threadIdx.x;
    if (i < n) rowptr[i + 1] += blksum[b];
}

__global__ void fill_kernel(const int* __restrict__ src, const int* __restrict__ dst,
                            const int* __restrict__ rowptr, int* __restrict__ off,
                            int* __restrict__ col, int E)
{
    const int e = blockIdx.x * blockDim.x + threadIdx.x;
    if (e < E) {
        const int d = dst[e];
        const int p = rowptr[d] + atomicAdd(&off[d], 1);
        col[p] = src[e];
    }
}

// ============================================================================
// agg for H=4, CHANNEL-SLICED: wave = (node, head-slice). Slice s gathers only
// bytes [s*256, s*256+256) of each h row -> per-phase working set 12.8 MB
// (vs 51.2). Phase-major block order (s = blk/NB) keeps one sub-table hot.
// Producer/consumer within wave via packed (src, w) int2 in LDS; relu fused.
// ============================================================================
__global__ __launch_bounds__(256) void agg4s_kernel(
    const bf16* __restrict__ h, const float* __restrict__ asrc,
    const float* __restrict__ adst, const int* __restrict__ rowptr,
    const int* __restrict__ col, const bf16* __restrict__ bias,
    bf16* __restrict__ out, int NB)
{
    __shared__ int2 ew_s[4][64];
    const int w = threadIdx.x >> 6, lane = threadIdx.x & 63;
    const int s = blockIdx.x / NB;            // slice == head (phase-major)
    const int n = (blockIdx.x % NB) * 4 + w;  // NB*4 == NNODES exactly
    const float ad = adst[(long)n * 4 + s];
    const int start = rowptr[n];
    const int deg   = rowptr[n + 1] - start;
    const int total = deg + 1;                // + virtual self-loop

    float z = 0.f, acc0 = 0.f, acc1 = 0.f;
    const bf16* hp = h + (long)s * 128 + lane * 2;

    for (int base = 0; base < total; base += 64) {
        // producer: lane handles edge (base+lane)
        const int i = base + lane;
        const bool valid = i < total;
        const int sv = (i < deg) ? col[start + i] : n;
        float e = asrc[(long)sv * 4 + s] + ad;
        e = (e > 0.f) ? e : 0.2f * e;
        e = fminf(fmaxf(e, -60.f), 60.f);
        const float wv = valid ? __expf(e) : 0.f;
        ew_s[w][lane] = make_int2(sv, __float_as_int(wv));
        __builtin_amdgcn_wave_barrier();
        // consumer: sweep chunk; 4B gather per lane (256B/row-slice per wave)
        const int cnt = min(64, total - base);
#pragma unroll 4
        for (int j = 0; j < cnt; j++) {
            const int2 v = ew_s[w][j];
            const float ww = __int_as_float(v.y);
            z += ww;
            const bf16x2 hv = *(const bf16x2*)(hp + (long)v.x * 512);
            acc0 += ww * (float)hv[0];
            acc1 += ww * (float)hv[1];
        }
        __builtin_amdgcn_wave_barrier();
    }

    const float rz = 1.f / (z + 1e-16f);
    const bf16x2 b2 = *(const bf16x2*)(bias + s * 128 + lane * 2);
    bf16x2 ov;
    ov[0] = (bf16)fmaxf(acc0 * rz + (float)b2[0], 0.f);   // relu fused
    ov[1] = (bf16)fmaxf(acc1 * rz + (float)b2[1], 0.f);
    *(bf16x2*)(out + (long)n * 512 + s * 128 + lane * 2) = ov;
}

// ============================================================================
// agg H=1 (layer 2): wave-per-node producer/consumer (R4-verified)
// ============================================================================
template <int H>
__global__ __launch_bounds__(256) void agg_kernel(
    const bf16* __restrict__ h, const float* __restrict__ asrc,
    const float* __restrict__ adst, const int* __restrict__ rowptr,
    const int* __restrict__ col, const bf16* __restrict__ bias,
    void* __restrict__ outv, const int* __restrict__ dflag, int relu)
{
    constexpr int HC  = H * 128;
    constexpr int VPL = HC / 64;              // channels per lane
    typedef __bf16 vec_t __attribute__((ext_vector_type(VPL)));
    __shared__ float wt_s[4][64][H];
    __shared__ int   sv_s[4][64];
    const int w = threadIdx.x >> 6, lane = threadIdx.x & 63;
    const int n = blockIdx.x * 4 + w;
    if (n >= NNODES) return;
    const int fp32out = dflag ? *dflag : 0;
    const int hol = (lane * VPL) >> 7;        // head of this lane's channels

    float ad[H];
    if (H == 4) {
        const float4 d4 = *(const float4*)(adst + (long)n * 4);
        ad[0] = d4.x; ad[1] = d4.y; ad[2] = d4.z; ad[3] = d4.w;
    } else {
        ad[0] = adst[n];
    }
    const int start = rowptr[n];
    const int deg   = rowptr[n + 1] - start;
    const int total = deg + 1;                // + virtual self-loop

    float z = 0.f;
    float accv[VPL];
#pragma unroll
    for (int j = 0; j < VPL; j++) accv[j] = 0.f;
    const bf16* hp = h + (long)lane * VPL;

    for (int base = 0; base < total; base += 64) {
        const int i = base + lane;
        const bool valid = i < total;
        const int s = (i < deg) ? col[start + i] : n;
        float wv[H];
        if (H == 4) {
            const float4 a4 = *(const float4*)(asrc + (long)s * 4);
            wv[0] = a4.x; wv[1] = a4.y; wv[2] = a4.z; wv[3] = a4.w;
        } else {
            wv[0] = asrc[s];
        }
#pragma unroll
        for (int hh = 0; hh < H; hh++) {
            float e = wv[hh] + ad[hh];
            e = (e > 0.f) ? e : 0.2f * e;
            e = fminf(fmaxf(e, -60.f), 60.f);
            wv[hh] = valid ? __expf(e) : 0.f;
        }
        sv_s[w][lane] = s;
#pragma unroll
        for (int hh = 0; hh < H; hh++) wt_s[w][lane][hh] = wv[hh];
        __builtin_amdgcn_wave_barrier();

        const int cnt = min(64, total - base);
#pragma unroll 4
        for (int j = 0; j < cnt; j++) {
            const int ss = sv_s[w][j];           // broadcast read
            const float ww = wt_s[w][j][hol];    // broadcast per 16-group
            z += ww;
            const vec_t hv = *(const vec_t*)(hp + (long)ss * HC);
#pragma unroll
            for (int jj = 0; jj < VPL; jj++) accv[jj] += ww * (float)hv[jj];
        }
        __builtin_amdgcn_wave_barrier();
    }

    const float rz = 1.f / (z + 1e-16f);
    const long obase = (long)n * HC + lane * VPL;
    if (fp32out) {
        float* op = (float*)outv;
#pragma unroll
        for (int j = 0; j < VPL; j++) {
            float o = accv[j] * rz + (float)bias[lane * VPL + j];
            if (relu) o = fmaxf(o, 0.f);
            op[obase + j] = o;
        }
    } else {
        vec_t ov;
#pragma unroll
        for (int j = 0; j < VPL; j++) {
            float o = accv[j] * rz + (float)bias[lane * VPL + j];
            if (relu) o = fmaxf(o, 0.f);
            ov[j] = (bf16)o;
        }
        *(vec_t*)((bf16*)outv + obase) = ov;
    }
}

// ============================================================================
// Output heads from d_out section 0 (dtype per flag); writes sections 1,2
// ============================================================================
__global__ __launch_bounds__(256) void heads_kernel(
    const void* __restrict__ hbase, void* __restrict__ outv,
    const bf16* __restrict__ Wv, const bf16* __restrict__ bv,
    const bf16* __restrict__ Wt, const bf16* __restrict__ bt,
    const int* __restrict__ dflag, int N)
{
    const int fp32 = *dflag;
    __shared__ float hbuf[32][128];
    const int n0 = blockIdx.x * 32, t = threadIdx.x;
    for (int i = t; i < 32 * 128; i += 256) {
        const int node = n0 + (i >> 7), c = i & 127;
        float v = 0.f;
        if (node < N)
            v = fp32 ? ((const float*)hbase)[(long)node * 128 + c]
                     : (float)((const bf16*)hbase)[(long)node * 128 + c];
        hbuf[i >> 7][c] = v;
    }
    __syncthreads();
    const int m = t & 127;
    const bool vis = t < 128;
    const bf16* W = vis ? Wv : Wt;
    const float b = (float)(vis ? bv[m] : bt[m]);
    float acc[32];
#pragma unroll
    for (int i = 0; i < 32; i++) acc[i] = 0.f;
    for (int k0 = 0; k0 < 128; k0 += 8) {
        const bf16x8 wv8 = *(const bf16x8*)&W[m * 128 + k0];
#pragma unroll
        for (int kk = 0; kk < 8; kk++) {
            const float wk = (float)wv8[kk];
#pragma unroll
            for (int i = 0; i < 32; i++) acc[i] += hbuf[i][k0 + kk] * wk;
        }
    }
    const long sec = vis ? (long)N * 128 : (long)2 * N * 128;
#pragma unroll
    for (int i = 0; i < 32; i++) {
        const int node = n0 + i;
        if (node < N) {
            float o = fmaxf(acc[i] + b, 0.f);
            const long idx = sec + (long)node * 128 + m;
            if (fp32) ((float*)outv)[idx] = o;
            else ((bf16*)outv)[idx] = (bf16)o;
        }
    }
}

// ============================================================================
extern "C" void kernel_launch(void* const* d_in, const int* in_sizes, int n_in,
                              void* d_out, int out_size, void* d_ws, size_t ws_size,
                              hipStream_t stream)
{
    const int N = NNODES, E = NEDGES;
    const int* srcp = (const int*)d_in[1];
    const int* dstp = srcp + E;

    char* p0 = (char*)d_ws;
    char* p = p0;
    auto bump = [&](size_t b) { char* r = p; p += (b + 255) & ~(size_t)255; return r; };
    int*   dflag  = (int*)bump(256);
    bf16*  xc     = (bf16*)bump((size_t)N * 512 * 2);
    bf16*  W0c    = (bf16*)bump(262144 * 2);
    bf16*  as0c   = (bf16*)bump(512 * 2);
    bf16*  ad0c   = (bf16*)bump(512 * 2);
    bf16*  b0c    = (bf16*)bump(512 * 2);
    bf16*  W1c    = (bf16*)bump(262144 * 2);
    bf16*  as1c   = (bf16*)bump(512 * 2);
    bf16*  ad1c   = (bf16*)bump(512 * 2);
    bf16*  b1c    = (bf16*)bump(512 * 2);
    bf16*  W2c    = (bf16*)bump(65536 * 2);
    bf16*  as2c   = (bf16*)bump(128 * 2);
    bf16*  ad2c   = (bf16*)bump(128 * 2);
    bf16*  b2c    = (bf16*)bump(128 * 2);
    bf16*  Wvc    = (bf16*)bump(16384 * 2);
    bf16*  bvc    = (bf16*)bump(128 * 2);
    bf16*  Wtc    = (bf16*)bump(16384 * 2);
    bf16*  btc    = (bf16*)bump(128 * 2);
    int*   cnt    = (int*)bump((size_t)N * 4);
    int*   offs   = (int*)bump((size_t)N * 4);
    int*   rowptr = (int*)bump((size_t)(N + 1) * 4);
    int*   blksum = (int*)bump(256 * 4);
    int*   colarr = (int*)bump((size_t)E * 4);
    float* alphaS = (float*)bump((size_t)N * 4 * 4);
    float* alphaD = (float*)bump((size_t)N * 4 * 4);
    bf16*  bufA   = (bf16*)bump((size_t)N * 512 * 2);
    bf16*  bufB   = (bf16*)bump((size_t)N * 512 * 2);
    const size_t need = (size_t)(p - p0);

    detect_kernel<<<1, 64, 0, stream>>>((const unsigned int*)d_in[0], dflag);

    if (need > ws_size) {  // diagnostic fallback: zero output
        zero_out_kernel<<<((long)out_size + 255) / 256, 256, 0, stream>>>(d_out, out_size, dflag);
        return;
    }

    // convert all float tensors to bf16 working copies
    convert_kernel<<<(N * 512 + 255) / 256, 256, 0, stream>>>(d_in[0], xc, N * 512, dflag);
    CvtBatch cb;
    const void* ins[16] = {d_in[2], d_in[3], d_in[4], d_in[5], d_in[6], d_in[7], d_in[8], d_in[9],
                           d_in[10], d_in[11], d_in[12], d_in[13], d_in[14], d_in[15], d_in[16], d_in[17]};
    bf16* outs[16] = {W0c, as0c, ad0c, b0c, W1c, as1c, ad1c, b1c,
                      W2c, as2c, ad2c, b2c, Wvc, bvc, Wtc, btc};
    const int ns[16] = {262144, 512, 512, 512, 262144, 512, 512, 512,
                        65536, 128, 128, 128, 16384, 128, 16384, 128};
    for (int i = 0; i < 16; i++) { cb.in[i] = ins[i]; cb.out[i] = outs[i]; cb.n[i] = ns[i]; }
    convert_batch_kernel<<<dim3(256, 16), 256, 0, stream>>>(cb, dflag);

    // CSR by destination
    const int nb = (N + 255) / 256;  // 196
    hipMemsetAsync(cnt, 0, (size_t)N * 4, stream);
    hipMemsetAsync(offs, 0, (size_t)N * 4, stream);
    hist_kernel<<<(E + 255) / 256, 256, 0, stream>>>(dstp, cnt, E);
    scan1_kernel<<<nb, 256, 0, stream>>>(cnt, rowptr, blksum, N);
    scan2_kernel<<<1, 256, 0, stream>>>(blksum, nb);
    scan3_kernel<<<nb, 256, 0, stream>>>(rowptr, blksum, N);
    fill_kernel<<<(E + 255) / 256, 256, 0, stream>>>(srcp, dstp, rowptr, offs, colarr, E);

    const int NB = N / 4;  // 12500 node-blocks (4 nodes each), N%4==0

    // Layer 0   (gemm grid: x = N-tiles, y = M-tiles -> A-tile reuse)
    dim3 g0(4, (N + 127) / 128);
    gemm_bt<<<g0, 256, 0, stream>>>(xc, W0c, bufA, N, 512, 512);
    alpha_kernel<4><<<N, 256, 0, stream>>>(bufA, as0c, ad0c, alphaS, alphaD);
    agg4s_kernel<<<NB * 4, 256, 0, stream>>>(bufA, alphaS, alphaD, rowptr, colarr, b0c, bufB, NB);

    // Layer 1
    gemm_bt<<<g0, 256, 0, stream>>>(bufB, W1c, bufA, N, 512, 512);
    alpha_kernel<4><<<N, 256, 0, stream>>>(bufA, as1c, ad1c, alphaS, alphaD);
    agg4s_kernel<<<NB * 4, 256, 0, stream>>>(bufA, alphaS, alphaD, rowptr, colarr, b1c, bufB, NB);

    // Layer 2 (heads=1) -> d_out section 0 (dtype per flag)
    dim3 g2(1, (N + 127) / 128);
    gemm_bt<<<g2, 256, 0, stream>>>(bufB, W2c, bufA, N, 128, 512);
    alpha_kernel<1><<<N, 64, 0, stream>>>(bufA, as2c, ad2c, alphaS, alphaD);
    agg_kernel<1><<<(N + 3) / 4, 256, 0, stream>>>(bufA, alphaS, alphaD, rowptr, colarr, b2c, d_out, dflag, 0);

    // Output heads -> sections 1,2
    heads_kernel<<<(N + 31) / 32, 256, 0, stream>>>(d_out, d_out, Wvc, bvc, Wtc, btc, dflag, N);
}